// Round 11
// baseline (48.422 us; speedup 1.0000x reference)
//
#include <hip/hip_runtime.h>
#include <math.h>

#define NC 15

struct Params {
    const float* p1[3];
    const float* p1d[3];
    const float* p2[3];
    const float* p2d[3];
    const float* lb[3];
    double* sums;   // [48 groups][8 buckets][10 terms]
};

__device__ __forceinline__ float rcp_f(float x) { return __builtin_amdgcn_rcpf(x); }

__device__ __forceinline__ void stage16(const float* g, float* l) {
    __builtin_amdgcn_global_load_lds(
        (const __attribute__((address_space(1))) void*)g,
        (__attribute__((address_space(3))) void*)l, 16, 0, 0);
}
__device__ __forceinline__ void stage4(const float* g, float* l) {
    __builtin_amdgcn_global_load_lds(
        (const __attribute__((address_space(1))) void*)g,
        (__attribute__((address_space(3))) void*)l, 4, 0, 0);
}

__device__ __forceinline__ float focal_f(float x, float t) {
    float e = __expf(-fabsf(x));
    float rc = rcp_f(1.0f + e);
    float sp = __logf(1.0f + e);
    float bce = fmaxf(x, 0.0f) - x * t + sp;
    float sig = (x >= 0.0f ? 1.0f : e) * rc;
    float d = t - sig;
    return bce * d * d;
}
__device__ __forceinline__ float sl1_f(float x, float t) {
    float n = fabsf(x - t);
    return n < 1.0f ? 0.5f * n * n : n - 0.5f;
}

__device__ __forceinline__ float giou_f(float bx, float by, float bz, float bw,
                                        float lx, float ly, float lw, float lh) {
    float b1x0 = bx - bz * 0.5f, b1y0 = by - bw * 0.5f;
    float b1x1 = bx + bz * 0.5f, b1y1 = by + bw * 0.5f;
    float b2x0 = lx - lw * 0.5f, b2y0 = ly - lh * 0.5f;
    float b2x1 = lx + lw * 0.5f, b2y1 = ly + lh * 0.5f;
    float ax0 = fminf(b1x0, b1x1), ay0 = fminf(b1y0, b1y1);
    float ax1 = fmaxf(b1x0, b1x1), ay1 = fmaxf(b1y0, b1y1);
    float cx0 = fminf(b2x0, b2x1), cy0 = fminf(b2y0, b2y1);
    float cx1 = fmaxf(b2x0, b2x1), cy1 = fmaxf(b2y0, b2y1);
    float a1 = (ax1 - ax0) * (ay1 - ay0);
    float a2 = (cx1 - cx0) * (cy1 - cy0);
    float ltx = fmaxf(ax0, cx0), lty = fmaxf(ay0, cy0);
    float rbx = fminf(ax1, cx1), rby = fminf(ay1, cy1);
    float iw = fmaxf(rbx - ltx, 0.0f), ih = fmaxf(rby - lty, 0.0f);
    float inter = iw * ih;
    float uni = a1 + a2 - inter;
    float iou = inter * rcp_f(uni + 1e-6f);
    float ex0 = fminf(ax0, cx0), ey0 = fminf(ay0, cy0);
    float ex1 = fmaxf(ax1, cx1), ey1 = fmaxf(ay1, cy1);
    float ew = fmaxf(ex1 - ex0, 0.0f), eh = fmaxf(ey1 - ey0, 0.0f);
    float enc = ew * eh;
    return iou - (enc - uni) * rcp_f(enc + 1e-6f);
}

// One wave (64 threads) per block, 64 cells. ALL inputs staged to LDS via
// global_load_lds (zero staging VGPRs -> one latency wait per wave; linear
// coalesced source addresses -> 16 lines/inst instead of ~64).
__global__ __launch_bounds__(64, 2) void loss_all(Params P) {
    __shared__ __align__(16) float sL[1984];   // label 31*64
    __shared__ __align__(16) float sA[832];    // p1d  13*64
    __shared__ __align__(16) float sB[832];    // p2d  13*64
    __shared__ __align__(16) float sQ[1600];   // p2   25*64
    __shared__ __align__(16) float sC[64];     // p1 conf

    int lane = threadIdx.x;
    int bid = blockIdx.x;
    int lvl, lblk, shift;
    float invStride;
    if (bid >= 5120)      { lvl = 2; lblk = bid - 5120; shift = 10; invStride = 1.0f / 32.0f; }
    else if (bid >= 4096) { lvl = 1; lblk = bid - 4096; shift = 12; invStride = 1.0f / 16.0f; }
    else                  { lvl = 0; lblk = bid;        shift = 14; invStride = 1.0f / 8.0f;  }
    int cell0 = lblk << 6;
    int c = cell0 + lane;
    int batch = c >> shift;   // uniform across wave

    const float* gL = P.lb[lvl]  + (size_t)cell0 * 31;   // 496 v4
    const float* gA = P.p1d[lvl] + (size_t)cell0 * 13;   // 208 v4
    const float* gB = P.p2d[lvl] + (size_t)cell0 * 13;   // 208 v4
    const float* gQ = P.p2[lvl]  + (size_t)cell0 * 25;   // 400 v4

    // ---- single staging burst: 25 global_load_lds, no VGPR round-trip ----
#pragma unroll
    for (int k = 0; k < 7; ++k) stage16(gL + (size_t)(k * 64 + lane) * 4, sL + k * 256);
    if (lane < 48) stage16(gL + (size_t)(448 + lane) * 4, sL + 1792);
#pragma unroll
    for (int k = 0; k < 3; ++k) stage16(gA + (size_t)(k * 64 + lane) * 4, sA + k * 256);
    if (lane < 16) stage16(gA + (size_t)(192 + lane) * 4, sA + 768);
#pragma unroll
    for (int k = 0; k < 3; ++k) stage16(gB + (size_t)(k * 64 + lane) * 4, sB + k * 256);
    if (lane < 16) stage16(gB + (size_t)(192 + lane) * 4, sB + 768);
#pragma unroll
    for (int k = 0; k < 6; ++k) stage16(gQ + (size_t)(k * 64 + lane) * 4, sQ + k * 256);
    if (lane < 16) stage16(gQ + (size_t)(384 + lane) * 4, sQ + 1536);
    stage4(P.p1[lvl] + (size_t)c * 10 + 9, sC);

    asm volatile("s_waitcnt vmcnt(0)" ::: "memory");
    __builtin_amdgcn_sched_barrier(0);

    // ---- label extraction (stride 31: conflict-free) ----
    const float* L = sL + lane * 31;
    float lx = L[0], ly = L[1], lw = L[2], lh = L[3];
    float l1 = L[4], l2 = L[5], l3 = L[6], l4 = L[7];
    float a0 = L[8], a1 = L[9], a2 = L[10], a3 = L[11];
    float lr = L[12];
    float flag = L[13];
    float mix = L[14];
    float area = L[15];
    float gh = 0.0f;
    unsigned nzm = 0u;
#pragma unroll
    for (int k = 0; k < NC; ++k) {
        float cv = L[16 + k];
        gh = fmaxf(gh, cv);
        if (cv != 0.0f) nzm |= (1u << k);
    }

    float obj   = (flag == 1.0f) ? 1.0f : 0.0f;
    float noobj = (flag == 0.0f) ? 1.0f : 0.0f;
    float fuzzy = 1.0f - obj - noobj;
    float conf_t = obj * 0.99f + 0.005f;
    float aw = area + ((area == 0.0f) ? 1.0f : 0.0f);
    float bls = 2.0f - lw * lh * (1.0f / (1024.0f * 1024.0f));

    float v0, v1, v2, v3, v4, v5, v6, v7, v8, v9;

    // ---------------- head 1 ----------------
    {
        const float* A = sA + lane * 13;
        float xiou = giou_f(A[0], A[1], A[2], A[3], lx, ly, lw, lh);
        float siou = bls * (1.0f - fminf(fmaxf(xiou, 0.0f), 1.0f));
        float d0 = A[4] - a0, d1 = A[5] - a1, d2 = A[6] - a2, d3 = A[7] - a3;
        float sobb = d0 * d0 + d1 * d1 + d2 * d2 + d3 * d3;
        float dr = A[8] - lr;
        float sarea = dr * dr;
        float off = __expf(-(siou + sobb + sarea));
        float g = (gh + off) * 0.5f;
        float bg = noobj + fuzzy * ((g < 0.3f) ? 1.0f : 0.0f) * (1.0f - fuzzy * g);
        float fg = obj * ((g >= 0.3f) ? 1.0f : 0.0f);
        float foc = focal_f(sC[lane], conf_t);
        float fma_ = fg * mix * aw;
        v0 = fg * foc * mix * g;
        v1 = bg * foc * mix;
        v2 = fma_ * siou;
        v3 = fma_ * sobb;
        v4 = fma_ * sarea;
        float sl = sl1_f(A[9] * invStride,  l1 * invStride)
                 + sl1_f(A[10] * invStride, l2 * invStride)
                 + sl1_f(A[11] * invStride, l3 * invStride)
                 + sl1_f(A[12] * invStride, l4 * invStride);
        v5 = fg * bls * sl * mix * aw;
    }

    // ---------------- head 2 ----------------
    {
        const float* B = sB + lane * 13;
        float xiou = giou_f(B[0], B[1], B[2], B[3], lx, ly, lw, lh);
        float siou2 = bls * (1.0f - fminf(fmaxf(xiou, 0.0f), 1.0f));
        float d0 = B[4] - a0, d1 = B[5] - a1, d2 = B[6] - a2, d3 = B[7] - a3;
        float sobb2 = d0 * d0 + d1 * d1 + d2 * d2 + d3 * d3;
        float dr = B[8] - lr;
        float sarea2 = dr * dr;
        float off2 = __expf(-(siou2 + sobb2 + sarea2));
        float sl2 = sl1_f(B[9] * invStride,  l1 * invStride)
                  + sl1_f(B[10] * invStride, l2 * invStride)
                  + sl1_f(B[11] * invStride, l3 * invStride)
                  + sl1_f(B[12] * invStride, l4 * invStride);

        const float* Q = sQ + lane * 25 + 9;
        float conf2 = Q[0];
        float g = (gh + off2) * 0.5f;
        float bg = noobj + fuzzy * ((g < 0.3f) ? 1.0f : 0.0f) * (1.0f - fuzzy * g);
        float fg = obj * ((g >= 0.3f) ? 1.0f : 0.0f);
        float foc = focal_f(conf2, conf_t);
        v0 += fg * foc * mix * g;
        v1 += bg * foc * mix;

        float pos = 0.0f, neg = 0.0f, wsum = 0.0f, clsb = 0.0f;
#pragma unroll
        for (int k = 0; k < NC; ++k) {
            float x = Q[1 + k];
            bool nz = (nzm >> k) & 1u;
            float smn = (nz ? 0.99f : 0.0f) + (0.01f / 15.0f);
            float e = __expf(-fabsf(x));
            float sp = __logf(1.0f + e);
            float mx = fmaxf(x, 0.0f);
            float b0 = mx - x * smn + sp;
            clsb += b0;
            if (nz) {
                pos += mx - x * (smn * off2) + sp;
                wsum += (x >= 0.0f ? 1.0f : e) * rcp_f(1.0f + e);
            } else {
                neg += b0;
            }
        }
        float wgq = (wsum + gh) * 0.5f;
        float oma = obj * mix * aw;
        v6 = oma * pos;
        v7 = oma * neg;
        float fmaw = fg * mix * aw * wgq;
        v2 += fmaw * siou2;
        v3 += fmaw * sobb2;
        v4 += fmaw * sarea2;
        v5 += fg * bls * sl2 * mix * aw * wgq;
        v8 = fg * clsb * mix * aw;
    }
    v9 = obj;

    // ---- wave reduction; lane 0 -> 10 f64 atomics (8-way bucketed) ----
#pragma unroll
    for (int o = 32; o > 0; o >>= 1) {
        v0 += __shfl_down(v0, o);
        v1 += __shfl_down(v1, o);
        v2 += __shfl_down(v2, o);
        v3 += __shfl_down(v3, o);
        v4 += __shfl_down(v4, o);
        v5 += __shfl_down(v5, o);
        v6 += __shfl_down(v6, o);
        v7 += __shfl_down(v7, o);
        v8 += __shfl_down(v8, o);
        v9 += __shfl_down(v9, o);
    }
    if (lane == 0) {
        double* s = P.sums + ((size_t)(((lvl << 4) + batch) * 8 + (lblk & 7))) * 10;
        atomicAdd(s + 0, (double)v0);
        atomicAdd(s + 1, (double)v1);
        atomicAdd(s + 2, (double)v2);
        atomicAdd(s + 3, (double)v3);
        atomicAdd(s + 4, (double)v4);
        atomicAdd(s + 5, (double)v5);
        atomicAdd(s + 6, (double)v6);
        atomicAdd(s + 7, (double)v7);
        atomicAdd(s + 8, (double)v8);
        atomicAdd(s + 9, (double)v9);
    }
}

__global__ __launch_bounds__(64) void finalize_kernel(const double* __restrict__ S,
                                                      float* __restrict__ out) {
    int lane = threadIdx.x;
    double loc[10];
#pragma unroll
    for (int t = 0; t < 10; ++t) loc[t] = 0.0;
    if (lane < 48) {
        const double* s = S + (size_t)lane * 80;
        double acc[10];
#pragma unroll
        for (int t = 0; t < 10; ++t) acc[t] = 0.0;
        for (int b = 0; b < 8; ++b)
#pragma unroll
            for (int t = 0; t < 10; ++t) acc[t] += s[b * 10 + t];
        double invN = 1.0 / fmax(acc[9], 1.0);
#pragma unroll
        for (int t = 0; t < 9; ++t) loc[t] = acc[t] * invN;
    }
#pragma unroll
    for (int t = 0; t < 9; ++t) {
#pragma unroll
        for (int o = 32; o > 0; o >>= 1) loc[t] += __shfl_down(loc[t], o);
    }
    if (lane == 0) {
        const double invB = 1.0 / 16.0;
        double fg  = loc[0] * invB;
        double bg  = loc[1] * invB;
        double iou = loc[2] * invB * 0.5;
        double s_  = loc[3] * invB * 0.5;
        double r   = loc[4] * invB * 8.0;    // 16 * avg-of-2
        double l   = loc[5] * invB * 0.1;    // 0.2 * avg-of-2
        double pos = loc[6] * invB * 28.0;   // *(NC-1)=14, then *2
        double neg = loc[7] * invB * 2.0;
        double cls = loc[8] * invB;
        double loss = fg + bg + iou + s_ + r + pos + neg + l;
        out[0] = (float)loss; out[1] = (float)fg; out[2] = (float)bg;
        out[3] = (float)pos;  out[4] = (float)neg; out[5] = (float)iou;
        out[6] = (float)cls;  out[7] = (float)s_;  out[8] = (float)r;
        out[9] = (float)l;
    }
}

extern "C" void kernel_launch(void* const* d_in, const int* in_sizes, int n_in,
                              void* d_out, int out_size, void* d_ws, size_t ws_size,
                              hipStream_t stream) {
    (void)in_sizes; (void)n_in; (void)out_size; (void)ws_size;
    double* sums = (double*)d_ws;   // 48 * 8 * 10 doubles = 30720 B
    hipMemsetAsync(d_ws, 0, 48 * 8 * 10 * sizeof(double), stream);

    Params P;
    for (int lvl = 0; lvl < 3; ++lvl) {
        P.p1[lvl]  = (const float*)d_in[lvl * 5 + 0];
        P.p1d[lvl] = (const float*)d_in[lvl * 5 + 1];
        P.p2[lvl]  = (const float*)d_in[lvl * 5 + 2];
        P.p2d[lvl] = (const float*)d_in[lvl * 5 + 3];
        P.lb[lvl]  = (const float*)d_in[lvl * 5 + 4];
    }
    P.sums = sums;

    loss_all<<<dim3(5376), dim3(64), 0, stream>>>(P);
    finalize_kernel<<<dim3(1), dim3(64), 0, stream>>>(sums, (float*)d_out);
}

// Round 12
// 44.166 us; speedup vs baseline: 1.0964x; 1.0964x over previous
//
#include <hip/hip_runtime.h>
#include <math.h>

#define NC 15

typedef float f4_t __attribute__((ext_vector_type(4)));
typedef f4_t __attribute__((aligned(4))) u4_t;   // dword-aligned vec4 load

struct Params {
    const float* p1[3];
    const float* p1d[3];
    const float* p2[3];
    const float* p2d[3];
    const float* lb[3];
    double* sums;   // [48 groups][8 buckets][10 terms]
};

__device__ __forceinline__ float rcp_f(float x) { return __builtin_amdgcn_rcpf(x); }

__device__ __forceinline__ void stage16(const float* g, float* l) {
    __builtin_amdgcn_global_load_lds(
        (const __attribute__((address_space(1))) void*)g,
        (__attribute__((address_space(3))) void*)l, 16, 0, 0);
}

__device__ __forceinline__ float focal_f(float x, float t) {
    float e = __expf(-fabsf(x));
    float rc = rcp_f(1.0f + e);
    float sp = __logf(1.0f + e);
    float bce = fmaxf(x, 0.0f) - x * t + sp;
    float sig = (x >= 0.0f ? 1.0f : e) * rc;
    float d = t - sig;
    return bce * d * d;
}
__device__ __forceinline__ float sl1_f(float x, float t) {
    float n = fabsf(x - t);
    return n < 1.0f ? 0.5f * n * n : n - 0.5f;
}

__device__ __forceinline__ float giou_f(float bx, float by, float bz, float bw,
                                        float lx, float ly, float lw, float lh) {
    float b1x0 = bx - bz * 0.5f, b1y0 = by - bw * 0.5f;
    float b1x1 = bx + bz * 0.5f, b1y1 = by + bw * 0.5f;
    float b2x0 = lx - lw * 0.5f, b2y0 = ly - lh * 0.5f;
    float b2x1 = lx + lw * 0.5f, b2y1 = ly + lh * 0.5f;
    float ax0 = fminf(b1x0, b1x1), ay0 = fminf(b1y0, b1y1);
    float ax1 = fmaxf(b1x0, b1x1), ay1 = fmaxf(b1y0, b1y1);
    float cx0 = fminf(b2x0, b2x1), cy0 = fminf(b2y0, b2y1);
    float cx1 = fmaxf(b2x0, b2x1), cy1 = fmaxf(b2y0, b2y1);
    float a1 = (ax1 - ax0) * (ay1 - ay0);
    float a2 = (cx1 - cx0) * (cy1 - cy0);
    float ltx = fmaxf(ax0, cx0), lty = fmaxf(ay0, cy0);
    float rbx = fminf(ax1, cx1), rby = fminf(ay1, cy1);
    float iw = fmaxf(rbx - ltx, 0.0f), ih = fmaxf(rby - lty, 0.0f);
    float inter = iw * ih;
    float uni = a1 + a2 - inter;
    float iou = inter * rcp_f(uni + 1e-6f);
    float ex0 = fminf(ax0, cx0), ey0 = fminf(ay0, cy0);
    float ex1 = fmaxf(ax1, cx1), ey1 = fmaxf(ay1, cy1);
    float ew = fmaxf(ex1 - ex0, 0.0f), eh = fmaxf(ey1 - ey0, 0.0f);
    float enc = ew * eh;
    return iou - (enc - uni) * rcp_f(enc + 1e-6f);
}

// 128-thr blocks (2 independent waves, NO barriers). Per wave: label+p1d+p2d
// staged coalesced via global_load_lds into its own LDS region (single vmcnt
// wait); p2+conf direct strided. 29.2 KB LDS -> 5 blocks/CU (10 waves/CU,
// ~160 loads in flight/CU keeps MSHRs full).
__global__ __launch_bounds__(128, 2) void loss_all(Params P) {
    __shared__ __align__(16) float sL[2][1984];  // label 31*64 per wave
    __shared__ __align__(16) float sA[2][832];   // p1d 13*64 per wave
    __shared__ __align__(16) float sB[2][832];   // p2d 13*64 per wave

    int tid = threadIdx.x;
    int lane = tid & 63;
    int wid = tid >> 6;
    int bid = blockIdx.x;
    int lvl, lblk, shift;
    float invStride;
    if (bid >= 2560)      { lvl = 2; lblk = bid - 2560; shift = 10; invStride = 1.0f / 32.0f; }
    else if (bid >= 2048) { lvl = 1; lblk = bid - 2048; shift = 12; invStride = 1.0f / 16.0f; }
    else                  { lvl = 0; lblk = bid;        shift = 14; invStride = 1.0f / 8.0f;  }
    int cell0 = (lblk << 7) + (wid << 6);   // this wave's 64-cell chunk
    int c = cell0 + lane;
    int batch = c >> shift;                  // uniform across wave

    const float* gL = P.lb[lvl]  + (size_t)cell0 * 31;
    const float* gA = P.p1d[lvl] + (size_t)cell0 * 13;
    const float* gB = P.p2d[lvl] + (size_t)cell0 * 13;
    float* sLw = sL[wid];
    float* sAw = sA[wid];
    float* sBw = sB[wid];

    // ---- coalesced staging burst (zero staging VGPRs) ----
#pragma unroll
    for (int k = 0; k < 7; ++k) stage16(gL + (size_t)(k * 64 + lane) * 4, sLw + k * 256);
    if (lane < 48) stage16(gL + (size_t)(448 + lane) * 4, sLw + 1792);
#pragma unroll
    for (int k = 0; k < 3; ++k) stage16(gA + (size_t)(k * 64 + lane) * 4, sAw + k * 256);
    if (lane < 16) stage16(gA + (size_t)(192 + lane) * 4, sAw + 768);
#pragma unroll
    for (int k = 0; k < 3; ++k) stage16(gB + (size_t)(k * 64 + lane) * 4, sBw + k * 256);
    if (lane < 16) stage16(gB + (size_t)(192 + lane) * 4, sBw + 768);

    // ---- direct strided loads for p2 slice + p1 conf (in flight with staging) ----
    const float* pq = P.p2[lvl] + (size_t)c * 25 + 9;   // conf + 15 cls
    u4_t Q0 = *(const u4_t*)(pq + 0);
    u4_t Q1 = *(const u4_t*)(pq + 4);
    u4_t Q2 = *(const u4_t*)(pq + 8);
    u4_t Q3 = *(const u4_t*)(pq + 12);
    float conf1 = P.p1[lvl][(size_t)c * 10 + 9];

    asm volatile("s_waitcnt vmcnt(0)" ::: "memory");
    __builtin_amdgcn_sched_barrier(0);

    // ---- label extraction (stride 31: conflict-free) ----
    const float* L = sLw + lane * 31;
    float lx = L[0], ly = L[1], lw = L[2], lh = L[3];
    float l1 = L[4], l2 = L[5], l3 = L[6], l4 = L[7];
    float a0 = L[8], a1 = L[9], a2 = L[10], a3 = L[11];
    float lr = L[12];
    float flag = L[13];
    float mix = L[14];
    float area = L[15];
    float gh = 0.0f;
    unsigned nzm = 0u;
#pragma unroll
    for (int k = 0; k < NC; ++k) {
        float cv = L[16 + k];
        gh = fmaxf(gh, cv);
        if (cv != 0.0f) nzm |= (1u << k);
    }

    float obj   = (flag == 1.0f) ? 1.0f : 0.0f;
    float noobj = (flag == 0.0f) ? 1.0f : 0.0f;
    float fuzzy = 1.0f - obj - noobj;
    float conf_t = obj * 0.99f + 0.005f;
    float aw = area + ((area == 0.0f) ? 1.0f : 0.0f);
    float bls = 2.0f - lw * lh * (1.0f / (1024.0f * 1024.0f));

    float v0, v1, v2, v3, v4, v5, v6, v7, v8, v9;

    // ---------------- head 1 ----------------
    {
        const float* A = sAw + lane * 13;
        float xiou = giou_f(A[0], A[1], A[2], A[3], lx, ly, lw, lh);
        float siou = bls * (1.0f - fminf(fmaxf(xiou, 0.0f), 1.0f));
        float d0 = A[4] - a0, d1 = A[5] - a1, d2 = A[6] - a2, d3 = A[7] - a3;
        float sobb = d0 * d0 + d1 * d1 + d2 * d2 + d3 * d3;
        float dr = A[8] - lr;
        float sarea = dr * dr;
        float off = __expf(-(siou + sobb + sarea));
        float g = (gh + off) * 0.5f;
        float bg = noobj + fuzzy * ((g < 0.3f) ? 1.0f : 0.0f) * (1.0f - fuzzy * g);
        float fg = obj * ((g >= 0.3f) ? 1.0f : 0.0f);
        float foc = focal_f(conf1, conf_t);
        float fma_ = fg * mix * aw;
        v0 = fg * foc * mix * g;
        v1 = bg * foc * mix;
        v2 = fma_ * siou;
        v3 = fma_ * sobb;
        v4 = fma_ * sarea;
        float sl = sl1_f(A[9] * invStride,  l1 * invStride)
                 + sl1_f(A[10] * invStride, l2 * invStride)
                 + sl1_f(A[11] * invStride, l3 * invStride)
                 + sl1_f(A[12] * invStride, l4 * invStride);
        v5 = fg * bls * sl * mix * aw;
    }

    // ---------------- head 2 ----------------
    {
        const float* B = sBw + lane * 13;
        float xiou = giou_f(B[0], B[1], B[2], B[3], lx, ly, lw, lh);
        float siou2 = bls * (1.0f - fminf(fmaxf(xiou, 0.0f), 1.0f));
        float d0 = B[4] - a0, d1 = B[5] - a1, d2 = B[6] - a2, d3 = B[7] - a3;
        float sobb2 = d0 * d0 + d1 * d1 + d2 * d2 + d3 * d3;
        float dr = B[8] - lr;
        float sarea2 = dr * dr;
        float off2 = __expf(-(siou2 + sobb2 + sarea2));
        float sl2 = sl1_f(B[9] * invStride,  l1 * invStride)
                  + sl1_f(B[10] * invStride, l2 * invStride)
                  + sl1_f(B[11] * invStride, l3 * invStride)
                  + sl1_f(B[12] * invStride, l4 * invStride);

        float conf2 = Q0.x;
        float g = (gh + off2) * 0.5f;
        float bg = noobj + fuzzy * ((g < 0.3f) ? 1.0f : 0.0f) * (1.0f - fuzzy * g);
        float fg = obj * ((g >= 0.3f) ? 1.0f : 0.0f);
        float foc = focal_f(conf2, conf_t);
        v0 += fg * foc * mix * g;
        v1 += bg * foc * mix;

        float cx[NC] = {Q0.y, Q0.z, Q0.w, Q1.x, Q1.y, Q1.z, Q1.w,
                        Q2.x, Q2.y, Q2.z, Q2.w, Q3.x, Q3.y, Q3.z, Q3.w};
        float pos = 0.0f, neg = 0.0f, wsum = 0.0f, clsb = 0.0f;
#pragma unroll
        for (int k = 0; k < NC; ++k) {
            float x = cx[k];
            bool nz = (nzm >> k) & 1u;
            float smn = (nz ? 0.99f : 0.0f) + (0.01f / 15.0f);
            float e = __expf(-fabsf(x));
            float sp = __logf(1.0f + e);
            float mx = fmaxf(x, 0.0f);
            float b0 = mx - x * smn + sp;
            clsb += b0;
            if (nz) {
                pos += mx - x * (smn * off2) + sp;
                wsum += (x >= 0.0f ? 1.0f : e) * rcp_f(1.0f + e);
            } else {
                neg += b0;
            }
        }
        float wgq = (wsum + gh) * 0.5f;
        float oma = obj * mix * aw;
        v6 = oma * pos;
        v7 = oma * neg;
        float fmaw = fg * mix * aw * wgq;
        v2 += fmaw * siou2;
        v3 += fmaw * sobb2;
        v4 += fmaw * sarea2;
        v5 += fg * bls * sl2 * mix * aw * wgq;
        v8 = fg * clsb * mix * aw;
    }
    v9 = obj;

    // ---- per-wave reduction; lane 0 -> 10 f64 atomics (bucketed) ----
#pragma unroll
    for (int o = 32; o > 0; o >>= 1) {
        v0 += __shfl_down(v0, o);
        v1 += __shfl_down(v1, o);
        v2 += __shfl_down(v2, o);
        v3 += __shfl_down(v3, o);
        v4 += __shfl_down(v4, o);
        v5 += __shfl_down(v5, o);
        v6 += __shfl_down(v6, o);
        v7 += __shfl_down(v7, o);
        v8 += __shfl_down(v8, o);
        v9 += __shfl_down(v9, o);
    }
    if (lane == 0) {
        int bucket = ((lblk << 1) + wid) & 7;
        double* s = P.sums + ((size_t)(((lvl << 4) + batch) * 8 + bucket)) * 10;
        atomicAdd(s + 0, (double)v0);
        atomicAdd(s + 1, (double)v1);
        atomicAdd(s + 2, (double)v2);
        atomicAdd(s + 3, (double)v3);
        atomicAdd(s + 4, (double)v4);
        atomicAdd(s + 5, (double)v5);
        atomicAdd(s + 6, (double)v6);
        atomicAdd(s + 7, (double)v7);
        atomicAdd(s + 8, (double)v8);
        atomicAdd(s + 9, (double)v9);
    }
}

__global__ __launch_bounds__(64) void finalize_kernel(const double* __restrict__ S,
                                                      float* __restrict__ out) {
    int lane = threadIdx.x;
    double loc[10];
#pragma unroll
    for (int t = 0; t < 10; ++t) loc[t] = 0.0;
    if (lane < 48) {
        const double* s = S + (size_t)lane * 80;
        double acc[10];
#pragma unroll
        for (int t = 0; t < 10; ++t) acc[t] = 0.0;
        for (int b = 0; b < 8; ++b)
#pragma unroll
            for (int t = 0; t < 10; ++t) acc[t] += s[b * 10 + t];
        double invN = 1.0 / fmax(acc[9], 1.0);
#pragma unroll
        for (int t = 0; t < 9; ++t) loc[t] = acc[t] * invN;
    }
#pragma unroll
    for (int t = 0; t < 9; ++t) {
#pragma unroll
        for (int o = 32; o > 0; o >>= 1) loc[t] += __shfl_down(loc[t], o);
    }
    if (lane == 0) {
        const double invB = 1.0 / 16.0;
        double fg  = loc[0] * invB;
        double bg  = loc[1] * invB;
        double iou = loc[2] * invB * 0.5;
        double s_  = loc[3] * invB * 0.5;
        double r   = loc[4] * invB * 8.0;    // 16 * avg-of-2
        double l   = loc[5] * invB * 0.1;    // 0.2 * avg-of-2
        double pos = loc[6] * invB * 28.0;   // *(NC-1)=14, then *2
        double neg = loc[7] * invB * 2.0;
        double cls = loc[8] * invB;
        double loss = fg + bg + iou + s_ + r + pos + neg + l;
        out[0] = (float)loss; out[1] = (float)fg; out[2] = (float)bg;
        out[3] = (float)pos;  out[4] = (float)neg; out[5] = (float)iou;
        out[6] = (float)cls;  out[7] = (float)s_;  out[8] = (float)r;
        out[9] = (float)l;
    }
}

extern "C" void kernel_launch(void* const* d_in, const int* in_sizes, int n_in,
                              void* d_out, int out_size, void* d_ws, size_t ws_size,
                              hipStream_t stream) {
    (void)in_sizes; (void)n_in; (void)out_size; (void)ws_size;
    double* sums = (double*)d_ws;   // 48 * 8 * 10 doubles
    hipMemsetAsync(d_ws, 0, 48 * 8 * 10 * sizeof(double), stream);

    Params P;
    for (int lvl = 0; lvl < 3; ++lvl) {
        P.p1[lvl]  = (const float*)d_in[lvl * 5 + 0];
        P.p1d[lvl] = (const float*)d_in[lvl * 5 + 1];
        P.p2[lvl]  = (const float*)d_in[lvl * 5 + 2];
        P.p2d[lvl] = (const float*)d_in[lvl * 5 + 3];
        P.lb[lvl]  = (const float*)d_in[lvl * 5 + 4];
    }
    P.sums = sums;

    loss_all<<<dim3(2688), dim3(128), 0, stream>>>(P);
    finalize_kernel<<<dim3(1), dim3(64), 0, stream>>>(sums, (float*)d_out);
}

// Round 13
// 44.009 us; speedup vs baseline: 1.1003x; 1.0035x over previous
//
#include <hip/hip_runtime.h>
#include <math.h>

#define NC 15

typedef float f4_t __attribute__((ext_vector_type(4)));
typedef f4_t __attribute__((aligned(4))) u4_t;   // dword-aligned vec4 load (legal on CDNA)

struct Params {
    const float* p1[3];
    const float* p1d[3];
    const float* p2[3];
    const float* p2d[3];
    const float* lb[3];
    double* sums;   // [48 groups][10 terms]
};

__device__ __forceinline__ float rcp_f(float x) { return __builtin_amdgcn_rcpf(x); }

__device__ __forceinline__ u4_t nt4(const float* p) {
    return __builtin_nontemporal_load((const u4_t*)p);
}

__device__ __forceinline__ float focal_f(float x, float t) {
    float e = __expf(-fabsf(x));
    float rc = rcp_f(1.0f + e);
    float sp = __logf(1.0f + e);
    float bce = fmaxf(x, 0.0f) - x * t + sp;
    float sig = (x >= 0.0f ? 1.0f : e) * rc;
    float d = t - sig;
    return bce * d * d;
}
__device__ __forceinline__ float sl1_f(float x, float t) {
    float n = fabsf(x - t);
    return n < 1.0f ? 0.5f * n * n : n - 0.5f;
}

__device__ __forceinline__ float giou_f(f4_t b, float lx, float ly, float lw, float lh) {
    float b1x0 = b.x - b.z * 0.5f, b1y0 = b.y - b.w * 0.5f;
    float b1x1 = b.x + b.z * 0.5f, b1y1 = b.y + b.w * 0.5f;
    float b2x0 = lx - lw * 0.5f, b2y0 = ly - lh * 0.5f;
    float b2x1 = lx + lw * 0.5f, b2y1 = ly + lh * 0.5f;
    float ax0 = fminf(b1x0, b1x1), ay0 = fminf(b1y0, b1y1);
    float ax1 = fmaxf(b1x0, b1x1), ay1 = fmaxf(b1y0, b1y1);
    float cx0 = fminf(b2x0, b2x1), cy0 = fminf(b2y0, b2y1);
    float cx1 = fmaxf(b2x0, b2x1), cy1 = fmaxf(b2y0, b2y1);
    float a1 = (ax1 - ax0) * (ay1 - ay0);
    float a2 = (cx1 - cx0) * (cy1 - cy0);
    float ltx = fmaxf(ax0, cx0), lty = fmaxf(ay0, cy0);
    float rbx = fminf(ax1, cx1), rby = fminf(ay1, cy1);
    float iw = fmaxf(rbx - ltx, 0.0f), ih = fmaxf(rby - lty, 0.0f);
    float inter = iw * ih;
    float uni = a1 + a2 - inter;
    float iou = inter * rcp_f(uni + 1e-6f);
    float ex0 = fminf(ax0, cx0), ey0 = fminf(ay0, cy0);
    float ex1 = fmaxf(ax1, cx1), ey1 = fmaxf(ay1, cy1);
    float ew = fmaxf(ex1 - ex0, 0.0f), eh = fmaxf(ey1 - ey0, 0.0f);
    float enc = ew * eh;
    return iou - (enc - uni) * rcp_f(enc + 1e-6f);
}

__global__ __launch_bounds__(256, 5) void loss_all(Params P) {
    __shared__ __align__(16) float sL[7936];   // label: 256 cells * 31 floats
    __shared__ float red[4][10];

    int tid = threadIdx.x;
    int bid = blockIdx.x;
    int lvl, lblk, shift;
    float invStride;
    if (bid >= 1280)      { lvl = 2; lblk = bid - 1280; shift = 10; invStride = 1.0f / 32.0f; }
    else if (bid >= 1024) { lvl = 1; lblk = bid - 1024; shift = 12; invStride = 1.0f / 16.0f; }
    else                  { lvl = 0; lblk = bid;        shift = 14; invStride = 1.0f / 8.0f;  }
    int cell0 = lblk << 8;
    int c = cell0 + tid;
    int batch = c >> shift;   // uniform across block

    // ---- stage label coalesced through LDS ----
    {
        const float4* gLv = (const float4*)(P.lb[lvl] + (size_t)cell0 * 31);  // 1984 v4
        float4* vL = (float4*)sL;
#pragma unroll
        for (int k = 0; k < 7; ++k) vL[tid + 256 * k] = gLv[tid + 256 * k];
        if (tid < 192) vL[1792 + tid] = gLv[1792 + tid];
    }

    // ---- direct nontemporal (L1-bypass) vector loads for the strided slices ----
    const float* pa = P.p1d[lvl] + (size_t)c * 13;
    u4_t A0 = nt4(pa + 0);
    u4_t A1 = nt4(pa + 4);
    u4_t A2 = nt4(pa + 8);
    float A3 = __builtin_nontemporal_load(pa + 12);
    const float* pb = P.p2d[lvl] + (size_t)c * 13;
    u4_t B0 = nt4(pb + 0);
    u4_t B1 = nt4(pb + 4);
    u4_t B2 = nt4(pb + 8);
    float B3 = __builtin_nontemporal_load(pb + 12);
    const float* pq = P.p2[lvl] + (size_t)c * 25 + 9;   // conf + 15 cls
    u4_t Q0 = nt4(pq + 0);
    u4_t Q1 = nt4(pq + 4);
    u4_t Q2 = nt4(pq + 8);
    u4_t Q3 = nt4(pq + 12);
    float conf1 = __builtin_nontemporal_load(P.p1[lvl] + (size_t)c * 10 + 9);

    __syncthreads();

    // ---- label extraction from LDS (stride 31: conflict-free) ----
    const float* L = sL + tid * 31;
    float lx = L[0], ly = L[1], lw = L[2], lh = L[3];
    float l1 = L[4], l2 = L[5], l3 = L[6], l4 = L[7];
    float a0 = L[8], a1 = L[9], a2 = L[10], a3 = L[11];
    float lr = L[12];
    float flag = L[13];
    float mix = L[14];
    float area = L[15];
    float gh = 0.0f;
    unsigned nzm = 0u;
#pragma unroll
    for (int k = 0; k < NC; ++k) {
        float cv = L[16 + k];
        gh = fmaxf(gh, cv);
        if (cv != 0.0f) nzm |= (1u << k);
    }

    float obj   = (flag == 1.0f) ? 1.0f : 0.0f;
    float noobj = (flag == 0.0f) ? 1.0f : 0.0f;
    float fuzzy = 1.0f - obj - noobj;
    float conf_t = obj * 0.99f + 0.005f;
    float aw = area + ((area == 0.0f) ? 1.0f : 0.0f);
    float bls = 2.0f - lw * lh * (1.0f / (1024.0f * 1024.0f));

    float v0, v1, v2, v3, v4, v5, v6, v7, v8, v9;

    // ---------------- head 1 ----------------
    {
        float xiou = giou_f(A0, lx, ly, lw, lh);
        float siou = bls * (1.0f - fminf(fmaxf(xiou, 0.0f), 1.0f));
        float d0 = A1.x - a0, d1 = A1.y - a1, d2 = A1.z - a2, d3 = A1.w - a3;
        float sobb = d0 * d0 + d1 * d1 + d2 * d2 + d3 * d3;
        float dr = A2.x - lr;
        float sarea = dr * dr;
        float off = __expf(-(siou + sobb + sarea));
        float g = (gh + off) * 0.5f;
        float bg = noobj + fuzzy * ((g < 0.3f) ? 1.0f : 0.0f) * (1.0f - fuzzy * g);
        float fg = obj * ((g >= 0.3f) ? 1.0f : 0.0f);
        float foc = focal_f(conf1, conf_t);
        float fma_ = fg * mix * aw;
        v0 = fg * foc * mix * g;
        v1 = bg * foc * mix;
        v2 = fma_ * siou;
        v3 = fma_ * sobb;
        v4 = fma_ * sarea;
        float sl = sl1_f(A2.y * invStride, l1 * invStride)
                 + sl1_f(A2.z * invStride, l2 * invStride)
                 + sl1_f(A2.w * invStride, l3 * invStride)
                 + sl1_f(A3 * invStride,   l4 * invStride);
        v5 = fg * bls * sl * mix * aw;
    }

    // ---------------- head 2 ----------------
    {
        float xiou = giou_f(B0, lx, ly, lw, lh);
        float siou2 = bls * (1.0f - fminf(fmaxf(xiou, 0.0f), 1.0f));
        float d0 = B1.x - a0, d1 = B1.y - a1, d2 = B1.z - a2, d3 = B1.w - a3;
        float sobb2 = d0 * d0 + d1 * d1 + d2 * d2 + d3 * d3;
        float dr = B2.x - lr;
        float sarea2 = dr * dr;
        float off2 = __expf(-(siou2 + sobb2 + sarea2));
        float sl2 = sl1_f(B2.y * invStride, l1 * invStride)
                  + sl1_f(B2.z * invStride, l2 * invStride)
                  + sl1_f(B2.w * invStride, l3 * invStride)
                  + sl1_f(B3 * invStride,   l4 * invStride);

        float conf2 = Q0.x;
        float g = (gh + off2) * 0.5f;
        float bg = noobj + fuzzy * ((g < 0.3f) ? 1.0f : 0.0f) * (1.0f - fuzzy * g);
        float fg = obj * ((g >= 0.3f) ? 1.0f : 0.0f);
        float foc = focal_f(conf2, conf_t);
        v0 += fg * foc * mix * g;
        v1 += bg * foc * mix;

        float cx[NC] = {Q0.y, Q0.z, Q0.w, Q1.x, Q1.y, Q1.z, Q1.w,
                        Q2.x, Q2.y, Q2.z, Q2.w, Q3.x, Q3.y, Q3.z, Q3.w};
        float pos = 0.0f, neg = 0.0f, wsum = 0.0f, clsb = 0.0f;
#pragma unroll
        for (int k = 0; k < NC; ++k) {
            float x = cx[k];
            bool nz = (nzm >> k) & 1u;
            float smn = (nz ? 0.99f : 0.0f) + (0.01f / 15.0f);
            float e = __expf(-fabsf(x));
            float sp = __logf(1.0f + e);
            float mx = fmaxf(x, 0.0f);
            float b0 = mx - x * smn + sp;
            clsb += b0;
            if (nz) {
                pos += mx - x * (smn * off2) + sp;
                wsum += (x >= 0.0f ? 1.0f : e) * rcp_f(1.0f + e);
            } else {
                neg += b0;
            }
        }
        float wgq = (wsum + gh) * 0.5f;
        float oma = obj * mix * aw;
        v6 = oma * pos;
        v7 = oma * neg;
        float fmaw = fg * mix * aw * wgq;
        v2 += fmaw * siou2;
        v3 += fmaw * sobb2;
        v4 += fmaw * sarea2;
        v5 += fg * bls * sl2 * mix * aw * wgq;
        v8 = fg * clsb * mix * aw;
    }
    v9 = obj;

    // ---------------- reduction: wave shuffle -> LDS -> 10 f64 atomics ----------------
#pragma unroll
    for (int o = 32; o > 0; o >>= 1) {
        v0 += __shfl_down(v0, o);
        v1 += __shfl_down(v1, o);
        v2 += __shfl_down(v2, o);
        v3 += __shfl_down(v3, o);
        v4 += __shfl_down(v4, o);
        v5 += __shfl_down(v5, o);
        v6 += __shfl_down(v6, o);
        v7 += __shfl_down(v7, o);
        v8 += __shfl_down(v8, o);
        v9 += __shfl_down(v9, o);
    }
    int lane = tid & 63, wid = tid >> 6;
    if (lane == 0) {
        red[wid][0] = v0; red[wid][1] = v1; red[wid][2] = v2; red[wid][3] = v3;
        red[wid][4] = v4; red[wid][5] = v5; red[wid][6] = v6; red[wid][7] = v7;
        red[wid][8] = v8; red[wid][9] = v9;
    }
    __syncthreads();
    if (tid < 10) {
        float total = red[0][tid] + red[1][tid] + red[2][tid] + red[3][tid];
        atomicAdd(&P.sums[((size_t)((lvl << 4) + batch)) * 10 + tid], (double)total);
    }
}

__global__ __launch_bounds__(64) void finalize_kernel(const double* __restrict__ S,
                                                      float* __restrict__ out) {
    int lane = threadIdx.x;
    double loc[10];
#pragma unroll
    for (int t = 0; t < 10; ++t) loc[t] = 0.0;
    if (lane < 48) {
        const double* s = S + (size_t)lane * 10;
        double invN = 1.0 / fmax(s[9], 1.0);
#pragma unroll
        for (int t = 0; t < 9; ++t) loc[t] = s[t] * invN;
    }
#pragma unroll
    for (int t = 0; t < 9; ++t) {
#pragma unroll
        for (int o = 32; o > 0; o >>= 1) loc[t] += __shfl_down(loc[t], o);
    }
    if (lane == 0) {
        const double invB = 1.0 / 16.0;
        double fg  = loc[0] * invB;
        double bg  = loc[1] * invB;
        double iou = loc[2] * invB * 0.5;
        double s_  = loc[3] * invB * 0.5;
        double r   = loc[4] * invB * 8.0;    // 16 * avg-of-2
        double l   = loc[5] * invB * 0.1;    // 0.2 * avg-of-2
        double pos = loc[6] * invB * 28.0;   // *(NC-1)=14, then *2
        double neg = loc[7] * invB * 2.0;
        double cls = loc[8] * invB;
        double loss = fg + bg + iou + s_ + r + pos + neg + l;
        out[0] = (float)loss; out[1] = (float)fg; out[2] = (float)bg;
        out[3] = (float)pos;  out[4] = (float)neg; out[5] = (float)iou;
        out[6] = (float)cls;  out[7] = (float)s_;  out[8] = (float)r;
        out[9] = (float)l;
    }
}

extern "C" void kernel_launch(void* const* d_in, const int* in_sizes, int n_in,
                              void* d_out, int out_size, void* d_ws, size_t ws_size,
                              hipStream_t stream) {
    (void)in_sizes; (void)n_in; (void)out_size; (void)ws_size;
    double* sums = (double*)d_ws;   // 48 groups * 10 terms
    hipMemsetAsync(d_ws, 0, 48 * 10 * sizeof(double), stream);

    Params P;
    for (int lvl = 0; lvl < 3; ++lvl) {
        P.p1[lvl]  = (const float*)d_in[lvl * 5 + 0];
        P.p1d[lvl] = (const float*)d_in[lvl * 5 + 1];
        P.p2[lvl]  = (const float*)d_in[lvl * 5 + 2];
        P.p2d[lvl] = (const float*)d_in[lvl * 5 + 3];
        P.lb[lvl]  = (const float*)d_in[lvl * 5 + 4];
    }
    P.sums = sums;

    loss_all<<<dim3(1344), dim3(256), 0, stream>>>(P);
    finalize_kernel<<<dim3(1), dim3(64), 0, stream>>>(sums, (float*)d_out);
}

// Round 14
// 33.684 us; speedup vs baseline: 1.4375x; 1.3065x over previous
//
#include <hip/hip_runtime.h>
#include <math.h>

#define NC 15

typedef float f4_t __attribute__((ext_vector_type(4)));
typedef f4_t __attribute__((aligned(4))) u4_t;   // dword-aligned vec4 load (legal on CDNA)

struct Params {
    const float* p1[3];
    const float* p1d[3];
    const float* p2[3];
    const float* p2d[3];
    const float* lb[3];
    double* sums;   // [48 groups][10 terms]
};

__device__ __forceinline__ float rcp_f(float x) { return __builtin_amdgcn_rcpf(x); }

__device__ __forceinline__ float focal_f(float x, float t) {
    float e = __expf(-fabsf(x));
    float rc = rcp_f(1.0f + e);
    float sp = __logf(1.0f + e);
    float bce = fmaxf(x, 0.0f) - x * t + sp;
    float sig = (x >= 0.0f ? 1.0f : e) * rc;
    float d = t - sig;
    return bce * d * d;
}
__device__ __forceinline__ float sl1_f(float x, float t) {
    float n = fabsf(x - t);
    return n < 1.0f ? 0.5f * n * n : n - 0.5f;
}

__device__ __forceinline__ float giou_f(f4_t b, float lx, float ly, float lw, float lh) {
    float b1x0 = b.x - b.z * 0.5f, b1y0 = b.y - b.w * 0.5f;
    float b1x1 = b.x + b.z * 0.5f, b1y1 = b.y + b.w * 0.5f;
    float b2x0 = lx - lw * 0.5f, b2y0 = ly - lh * 0.5f;
    float b2x1 = lx + lw * 0.5f, b2y1 = ly + lh * 0.5f;
    float ax0 = fminf(b1x0, b1x1), ay0 = fminf(b1y0, b1y1);
    float ax1 = fmaxf(b1x0, b1x1), ay1 = fmaxf(b1y0, b1y1);
    float cx0 = fminf(b2x0, b2x1), cy0 = fminf(b2y0, b2y1);
    float cx1 = fmaxf(b2x0, b2x1), cy1 = fmaxf(b2y0, b2y1);
    float a1 = (ax1 - ax0) * (ay1 - ay0);
    float a2 = (cx1 - cx0) * (cy1 - cy0);
    float ltx = fmaxf(ax0, cx0), lty = fmaxf(ay0, cy0);
    float rbx = fminf(ax1, cx1), rby = fminf(ay1, cy1);
    float iw = fmaxf(rbx - ltx, 0.0f), ih = fmaxf(rby - lty, 0.0f);
    float inter = iw * ih;
    float uni = a1 + a2 - inter;
    float iou = inter * rcp_f(uni + 1e-6f);
    float ex0 = fminf(ax0, cx0), ey0 = fminf(ay0, cy0);
    float ex1 = fmaxf(ax1, cx1), ey1 = fmaxf(ay1, cy1);
    float ew = fmaxf(ex1 - ex0, 0.0f), eh = fmaxf(ey1 - ey0, 0.0f);
    float enc = ew * eh;
    return iou - (enc - uni) * rcp_f(enc + 1e-6f);
}

__global__ __launch_bounds__(256, 5) void loss_all(Params P) {
    __shared__ __align__(16) float sL[7936];   // label: 256 cells * 31 floats
    __shared__ float red[4][10];

    int tid = threadIdx.x;
    int bid = blockIdx.x;
    int lvl, lblk, shift;
    float invStride;
    if (bid >= 1280)      { lvl = 2; lblk = bid - 1280; shift = 10; invStride = 1.0f / 32.0f; }
    else if (bid >= 1024) { lvl = 1; lblk = bid - 1024; shift = 12; invStride = 1.0f / 16.0f; }
    else                  { lvl = 0; lblk = bid;        shift = 14; invStride = 1.0f / 8.0f;  }
    int cell0 = lblk << 8;
    int c = cell0 + tid;
    int batch = c >> shift;   // uniform across block

    // ---- stage label coalesced through LDS (the fat, transaction-heavy array) ----
    {
        const float4* gLv = (const float4*)(P.lb[lvl] + (size_t)cell0 * 31);  // 1984 v4, 16B-aligned
        float4* vL = (float4*)sL;
#pragma unroll
        for (int k = 0; k < 7; ++k) vL[tid + 256 * k] = gLv[tid + 256 * k];
        if (tid < 192) vL[1792 + tid] = gLv[1792 + tid];
    }

    // ---- direct register loads for the dense-use slices ----
    const float* pa = P.p1d[lvl] + (size_t)c * 13;
    u4_t A0 = *(const u4_t*)(pa + 0);
    u4_t A1 = *(const u4_t*)(pa + 4);
    u4_t A2 = *(const u4_t*)(pa + 8);
    float A3 = pa[12];
    const float* pb = P.p2d[lvl] + (size_t)c * 13;
    u4_t B0 = *(const u4_t*)(pb + 0);
    u4_t B1 = *(const u4_t*)(pb + 4);
    u4_t B2 = *(const u4_t*)(pb + 8);
    float B3 = pb[12];
    const float* pq = P.p2[lvl] + (size_t)c * 25 + 9;   // conf + 15 cls
    u4_t Q0 = *(const u4_t*)(pq + 0);
    u4_t Q1 = *(const u4_t*)(pq + 4);
    u4_t Q2 = *(const u4_t*)(pq + 8);
    u4_t Q3 = *(const u4_t*)(pq + 12);
    float conf1 = P.p1[lvl][(size_t)c * 10 + 9];

    __syncthreads();

    // ---- label extraction from LDS (stride 31: conflict-free, 2 lanes/bank) ----
    const float* L = sL + tid * 31;
    float lx = L[0], ly = L[1], lw = L[2], lh = L[3];
    float l1 = L[4], l2 = L[5], l3 = L[6], l4 = L[7];
    float a0 = L[8], a1 = L[9], a2 = L[10], a3 = L[11];
    float lr = L[12];
    float flag = L[13];
    float mix = L[14];
    float area = L[15];
    float gh = 0.0f;
    unsigned nzm = 0u;
#pragma unroll
    for (int k = 0; k < NC; ++k) {
        float cv = L[16 + k];
        gh = fmaxf(gh, cv);
        if (cv != 0.0f) nzm |= (1u << k);
    }

    float obj   = (flag == 1.0f) ? 1.0f : 0.0f;
    float noobj = (flag == 0.0f) ? 1.0f : 0.0f;
    float fuzzy = 1.0f - obj - noobj;
    float conf_t = obj * 0.99f + 0.005f;
    float aw = area + ((area == 0.0f) ? 1.0f : 0.0f);
    float bls = 2.0f - lw * lh * (1.0f / (1024.0f * 1024.0f));

    float v0, v1, v2, v3, v4, v5, v6, v7, v8, v9;

    // ---------------- head 1 ----------------
    {
        float xiou = giou_f(A0, lx, ly, lw, lh);
        float siou = bls * (1.0f - fminf(fmaxf(xiou, 0.0f), 1.0f));
        float d0 = A1.x - a0, d1 = A1.y - a1, d2 = A1.z - a2, d3 = A1.w - a3;
        float sobb = d0 * d0 + d1 * d1 + d2 * d2 + d3 * d3;
        float dr = A2.x - lr;
        float sarea = dr * dr;
        float off = __expf(-(siou + sobb + sarea));
        float g = (gh + off) * 0.5f;
        float bg = noobj + fuzzy * ((g < 0.3f) ? 1.0f : 0.0f) * (1.0f - fuzzy * g);
        float fg = obj * ((g >= 0.3f) ? 1.0f : 0.0f);
        float foc = focal_f(conf1, conf_t);
        float fma_ = fg * mix * aw;
        v0 = fg * foc * mix * g;
        v1 = bg * foc * mix;
        v2 = fma_ * siou;
        v3 = fma_ * sobb;
        v4 = fma_ * sarea;
        float sl = sl1_f(A2.y * invStride, l1 * invStride)
                 + sl1_f(A2.z * invStride, l2 * invStride)
                 + sl1_f(A2.w * invStride, l3 * invStride)
                 + sl1_f(A3 * invStride,   l4 * invStride);
        v5 = fg * bls * sl * mix * aw;
    }

    // ---------------- head 2 ----------------
    {
        float xiou = giou_f(B0, lx, ly, lw, lh);
        float siou2 = bls * (1.0f - fminf(fmaxf(xiou, 0.0f), 1.0f));
        float d0 = B1.x - a0, d1 = B1.y - a1, d2 = B1.z - a2, d3 = B1.w - a3;
        float sobb2 = d0 * d0 + d1 * d1 + d2 * d2 + d3 * d3;
        float dr = B2.x - lr;
        float sarea2 = dr * dr;
        float off2 = __expf(-(siou2 + sobb2 + sarea2));
        float sl2 = sl1_f(B2.y * invStride, l1 * invStride)
                  + sl1_f(B2.z * invStride, l2 * invStride)
                  + sl1_f(B2.w * invStride, l3 * invStride)
                  + sl1_f(B3 * invStride,   l4 * invStride);

        float conf2 = Q0.x;
        float g = (gh + off2) * 0.5f;
        float bg = noobj + fuzzy * ((g < 0.3f) ? 1.0f : 0.0f) * (1.0f - fuzzy * g);
        float fg = obj * ((g >= 0.3f) ? 1.0f : 0.0f);
        float foc = focal_f(conf2, conf_t);
        v0 += fg * foc * mix * g;
        v1 += bg * foc * mix;

        float cx[NC] = {Q0.y, Q0.z, Q0.w, Q1.x, Q1.y, Q1.z, Q1.w,
                        Q2.x, Q2.y, Q2.z, Q2.w, Q3.x, Q3.y, Q3.z, Q3.w};
        float pos = 0.0f, neg = 0.0f, wsum = 0.0f, clsb = 0.0f;
#pragma unroll
        for (int k = 0; k < NC; ++k) {
            float x = cx[k];
            bool nz = (nzm >> k) & 1u;
            float smn = (nz ? 0.99f : 0.0f) + (0.01f / 15.0f);
            float e = __expf(-fabsf(x));
            float sp = __logf(1.0f + e);
            float mx = fmaxf(x, 0.0f);
            float b0 = mx - x * smn + sp;
            clsb += b0;
            if (nz) {
                pos += mx - x * (smn * off2) + sp;
                wsum += (x >= 0.0f ? 1.0f : e) * rcp_f(1.0f + e);
            } else {
                neg += b0;
            }
        }
        float wgq = (wsum + gh) * 0.5f;
        float oma = obj * mix * aw;
        v6 = oma * pos;
        v7 = oma * neg;
        float fmaw = fg * mix * aw * wgq;
        v2 += fmaw * siou2;
        v3 += fmaw * sobb2;
        v4 += fmaw * sarea2;
        v5 += fg * bls * sl2 * mix * aw * wgq;
        v8 = fg * clsb * mix * aw;
    }
    v9 = obj;

    // ---------------- reduction: wave shuffle -> LDS -> 10 f64 atomics ----------------
#pragma unroll
    for (int o = 32; o > 0; o >>= 1) {
        v0 += __shfl_down(v0, o);
        v1 += __shfl_down(v1, o);
        v2 += __shfl_down(v2, o);
        v3 += __shfl_down(v3, o);
        v4 += __shfl_down(v4, o);
        v5 += __shfl_down(v5, o);
        v6 += __shfl_down(v6, o);
        v7 += __shfl_down(v7, o);
        v8 += __shfl_down(v8, o);
        v9 += __shfl_down(v9, o);
    }
    int lane = tid & 63, wid = tid >> 6;
    if (lane == 0) {
        red[wid][0] = v0; red[wid][1] = v1; red[wid][2] = v2; red[wid][3] = v3;
        red[wid][4] = v4; red[wid][5] = v5; red[wid][6] = v6; red[wid][7] = v7;
        red[wid][8] = v8; red[wid][9] = v9;
    }
    __syncthreads();
    if (tid < 10) {
        float total = red[0][tid] + red[1][tid] + red[2][tid] + red[3][tid];
        atomicAdd(&P.sums[((size_t)((lvl << 4) + batch)) * 10 + tid], (double)total);
    }
}

__global__ __launch_bounds__(64) void finalize_kernel(const double* __restrict__ S,
                                                      float* __restrict__ out) {
    int lane = threadIdx.x;
    double loc[10];
#pragma unroll
    for (int t = 0; t < 10; ++t) loc[t] = 0.0;
    if (lane < 48) {
        const double* s = S + (size_t)lane * 10;
        double invN = 1.0 / fmax(s[9], 1.0);
#pragma unroll
        for (int t = 0; t < 9; ++t) loc[t] = s[t] * invN;
    }
#pragma unroll
    for (int t = 0; t < 9; ++t) {
#pragma unroll
        for (int o = 32; o > 0; o >>= 1) loc[t] += __shfl_down(loc[t], o);
    }
    if (lane == 0) {
        const double invB = 1.0 / 16.0;
        double fg  = loc[0] * invB;
        double bg  = loc[1] * invB;
        double iou = loc[2] * invB * 0.5;
        double s_  = loc[3] * invB * 0.5;
        double r   = loc[4] * invB * 8.0;    // 16 * avg-of-2
        double l   = loc[5] * invB * 0.1;    // 0.2 * avg-of-2
        double pos = loc[6] * invB * 28.0;   // *(NC-1)=14, then *2
        double neg = loc[7] * invB * 2.0;
        double cls = loc[8] * invB;
        double loss = fg + bg + iou + s_ + r + pos + neg + l;
        out[0] = (float)loss; out[1] = (float)fg; out[2] = (float)bg;
        out[3] = (float)pos;  out[4] = (float)neg; out[5] = (float)iou;
        out[6] = (float)cls;  out[7] = (float)s_;  out[8] = (float)r;
        out[9] = (float)l;
    }
}

extern "C" void kernel_launch(void* const* d_in, const int* in_sizes, int n_in,
                              void* d_out, int out_size, void* d_ws, size_t ws_size,
                              hipStream_t stream) {
    (void)in_sizes; (void)n_in; (void)out_size; (void)ws_size;
    double* sums = (double*)d_ws;   // 48 groups * 10 terms
    hipMemsetAsync(d_ws, 0, 48 * 10 * sizeof(double), stream);

    Params P;
    for (int lvl = 0; lvl < 3; ++lvl) {
        P.p1[lvl]  = (const float*)d_in[lvl * 5 + 0];
        P.p1d[lvl] = (const float*)d_in[lvl * 5 + 1];
        P.p2[lvl]  = (const float*)d_in[lvl * 5 + 2];
        P.p2d[lvl] = (const float*)d_in[lvl * 5 + 3];
        P.lb[lvl]  = (const float*)d_in[lvl * 5 + 4];
    }
    P.sums = sums;

    loss_all<<<dim3(1344), dim3(256), 0, stream>>>(P);
    finalize_kernel<<<dim3(1), dim3(64), 0, stream>>>(sums, (float*)d_out);
}